// Round 4
// baseline (1220.387 us; speedup 1.0000x reference)
//
#include <hip/hip_runtime.h>

#define NN   12288
#define FIN  256
#define FOUT 128
#define ALPHA 0.2f

typedef __attribute__((ext_vector_type(8))) _Float16 half8v;
typedef __attribute__((ext_vector_type(4))) float float4v;
typedef __attribute__((ext_vector_type(4))) int   int4v;

// WhT2 layout: [node>>5][feat 0..127][node&31]  (_Float16)
//   -> one j-tile (32 nodes x 128 feats) is a contiguous 8 KB block.
// maskT layout: [node>>5][row i] (uint32), bit b of maskT[w][i] = adj[i][w*32+b]

// ---------------------------------------------------------------------------
// Kernel 1: Wh = h @ W (fp32): writes WhT2 (f16, j-tiled) + Wh1/Wh2 (fp32).
// One block = 16 nodes, 128 threads (thread t owns feature t).
// ---------------------------------------------------------------------------
__global__ __launch_bounds__(128) void k_wh(
    const float* __restrict__ h,
    const float* __restrict__ W,
    const float* __restrict__ a,
    _Float16* __restrict__ WhT2,
    float* __restrict__ Wh1, float* __restrict__ Wh2)
{
    __shared__ __align__(16) float hs[16 * FIN];   // 16 KB
    __shared__ float sP1[2][16], sP2[2][16];
    const int t = threadIdx.x;                     // 0..127
    const int row0 = blockIdx.x * 16;

    const float4v* hsrc = (const float4v*)(h + (size_t)row0 * FIN);
    float4v* hdst = (float4v*)hs;
    #pragma unroll
    for (int i = 0; i < 8; ++i) hdst[t + i * 128] = hsrc[t + i * 128];
    __syncthreads();

    float acc[16];
    #pragma unroll
    for (int r = 0; r < 16; ++r) acc[r] = 0.f;

    for (int k = 0; k < FIN; k += 4) {
        const float w0 = W[(k + 0) * FOUT + t];
        const float w1 = W[(k + 1) * FOUT + t];
        const float w2 = W[(k + 2) * FOUT + t];
        const float w3 = W[(k + 3) * FOUT + t];
        #pragma unroll
        for (int r = 0; r < 16; ++r) {
            const float4v hv = *(const float4v*)&hs[r * FIN + k];
            float s = acc[r];
            s = fmaf(hv.x, w0, s);
            s = fmaf(hv.y, w1, s);
            s = fmaf(hv.z, w2, s);
            s = fmaf(hv.w, w3, s);
            acc[r] = s;
        }
    }

    // WhT2[(row0+r)>>5][t][(row0+r)&31]; row0 mult of 16 -> contiguous r
    half8v pk0, pk1;
    #pragma unroll
    for (int r = 0; r < 8; ++r)  pk0[r] = (_Float16)acc[r];
    #pragma unroll
    for (int r = 0; r < 8; ++r)  pk1[r] = (_Float16)acc[8 + r];
    _Float16* dst = WhT2 + (size_t)(row0 >> 5) * 4096 + t * 32 + (row0 & 16);
    *(half8v*)(dst)     = pk0;
    *(half8v*)(dst + 8) = pk1;

    const float a1t = a[t];
    const float a2t = a[FOUT + t];
    const int lane = t & 63, wv = t >> 6;
    #pragma unroll
    for (int r = 0; r < 16; ++r) {
        float v1 = acc[r] * a1t;
        float v2 = acc[r] * a2t;
        #pragma unroll
        for (int off = 1; off < 64; off <<= 1) {
            v1 += __shfl_xor(v1, off, 64);
            v2 += __shfl_xor(v2, off, 64);
        }
        if (lane == 0) { sP1[wv][r] = v1; sP2[wv][r] = v2; }
    }
    __syncthreads();
    if (t < 16) {
        Wh1[row0 + t] = sP1[0][t] + sP1[1][t];
        Wh2[row0 + t] = sP2[0][t] + sP2[1][t];
    }
}

// ---------------------------------------------------------------------------
// Kernel 1b: maxWh2
// ---------------------------------------------------------------------------
__global__ __launch_bounds__(256) void k_max(
    const float* __restrict__ Wh2, float* __restrict__ outmax)
{
    __shared__ float sm[4];
    float m = -1e30f;
    for (int i = threadIdx.x; i < NN; i += 256) m = fmaxf(m, Wh2[i]);
    #pragma unroll
    for (int off = 1; off < 64; off <<= 1) m = fmaxf(m, __shfl_xor(m, off, 64));
    if ((threadIdx.x & 63) == 0) sm[threadIdx.x >> 6] = m;
    __syncthreads();
    if (threadIdx.x == 0)
        outmax[0] = fmaxf(fmaxf(sm[0], sm[1]), fmaxf(sm[2], sm[3]));
}

// ---------------------------------------------------------------------------
// Kernel 1c: pack adj -> transposed bitmask. Wave handles 4 rows; per iter
// lanes read 64 contiguous ints (coalesced), ballot -> 64 bits -> 2 words.
// ---------------------------------------------------------------------------
__global__ __launch_bounds__(256) void k_pack(
    const int* __restrict__ adj, unsigned int* __restrict__ maskT)
{
    const int wi = blockIdx.x * 4 + (threadIdx.x >> 6);
    const int lane = threadIdx.x & 63;
    for (int rr = 0; rr < 4; ++rr) {
        const int r = wi * 4 + rr;
        const int* row = adj + (size_t)r * NN;
        for (int it = 0; it < NN / 64; ++it) {
            const int v = row[it * 64 + lane];
            const unsigned long long b = __ballot(v != 0);
            const unsigned int myw = (lane == 0) ? (unsigned int)b
                                                 : (unsigned int)(b >> 32);
            if (lane < 2)
                maskT[(size_t)(it * 2 + lane) * NN + r] = myw;
        }
    }
}

// ---------------------------------------------------------------------------
// Kernel 2: fused masked-softmax attention + PV GEMM (partials).
// Block = 4 waves x 32 rows = 128 rows; all waves share the j-slice
// [jy*NN/J, ...). Per iter, the 8 KB WhT2 j-tile is double-buffer staged in
// LDS and consumed by all 4 waves (kills the L1-fill line bottleneck).
// Each wave: 2 row-groups (m, m+16); P built in MFMA A-layout in-register.
// Writes UN-normalized partial C + partial S; k_reduce finishes.
// ---------------------------------------------------------------------------
__global__ __launch_bounds__(256, 3) void k_attn(
    const unsigned int* __restrict__ maskT,
    const _Float16* __restrict__ WhT2,
    const float* __restrict__ Wh1, const float* __restrict__ Wh2,
    const float* __restrict__ maxp,
    float* __restrict__ pC, float* __restrict__ pS)
{
    __shared__ __align__(16) _Float16 tile[2][128 * 32];   // 2 x 8 KB
    const int tid  = threadIdx.x;
    const int w    = tid >> 6;
    const int lane = tid & 63;
    const int m    = lane & 15;
    const int q    = lane >> 4;
    const int rowbase = blockIdx.x * 128 + w * 32;
    const int J    = gridDim.y;
    const int jy   = blockIdx.y;
    const int jlen = NN / J;
    const int jbeg = jy * jlen;
    const int iters = jlen / 32;

    const float mxv  = maxp[0];
    const float wh1a = Wh1[rowbase + m];
    const float wh1b = Wh1[rowbase + 16 + m];
    const float tma = wh1a + mxv; const float Ma = fmaxf(tma, ALPHA * tma);
    const float tmb = wh1b + mxv; const float Mb = fmaxf(tmb, ALPHA * tmb);

    float4v c[2][8];
    #pragma unroll
    for (int rg = 0; rg < 2; ++rg)
        #pragma unroll
        for (int t = 0; t < 8; ++t) c[rg][t] = (float4v){0.f, 0.f, 0.f, 0.f};
    float Sa = 0.f, Sb = 0.f;

    // stage first tile
    {
        const float4v* src = (const float4v*)(WhT2 + (size_t)(jbeg >> 5) * 4096);
        float4v* dst = (float4v*)&tile[0][0];
        dst[tid * 2 + 0] = src[tid * 2 + 0];
        dst[tid * 2 + 1] = src[tid * 2 + 1];
    }
    __syncthreads();

    int buf = 0;
    for (int it = 0; it < iters; ++it) {
        const int j0 = jbeg + it * 32;
        const bool pre = (it + 1 < iters);
        float4v s0, s1;
        if (pre) {
            const float4v* src = (const float4v*)(WhT2 + (size_t)((j0 + 32) >> 5) * 4096);
            s0 = src[tid * 2 + 0];
            s1 = src[tid * 2 + 1];
        }

        const unsigned int mwa = maskT[(size_t)(j0 >> 5) * NN + rowbase + m];
        const unsigned int mwb = maskT[(size_t)(j0 >> 5) * NN + rowbase + 16 + m];
        const float4v w0 = *(const float4v*)(Wh2 + j0 + q * 8);
        const float4v w1 = *(const float4v*)(Wh2 + j0 + q * 8 + 4);
        const float wv[8] = {w0.x, w0.y, w0.z, w0.w, w1.x, w1.y, w1.z, w1.w};
        const unsigned int ba = mwa >> (q * 8);
        const unsigned int bb = mwb >> (q * 8);

        half8v afa, afb;
        #pragma unroll
        for (int jj = 0; jj < 8; ++jj) {
            float e = wh1a + wv[jj]; e = fmaxf(e, ALPHA * e);
            const float p = ((ba >> jj) & 1u) ? __expf(e - Ma) : 0.f;
            const _Float16 ph = (_Float16)p;
            afa[jj] = ph; Sa += (float)ph;
        }
        #pragma unroll
        for (int jj = 0; jj < 8; ++jj) {
            float e = wh1b + wv[jj]; e = fmaxf(e, ALPHA * e);
            const float p = ((bb >> jj) & 1u) ? __expf(e - Mb) : 0.f;
            const _Float16 ph = (_Float16)p;
            afb[jj] = ph; Sb += (float)ph;
        }

        half8v bfr[8];
        #pragma unroll
        for (int t = 0; t < 8; ++t)
            bfr[t] = *(const half8v*)&tile[buf][(t * 16 + m) * 32 + q * 8];

        #pragma unroll
        for (int t = 0; t < 8; ++t) {
            c[0][t] = __builtin_amdgcn_mfma_f32_16x16x32_f16(afa, bfr[t], c[0][t], 0, 0, 0);
            c[1][t] = __builtin_amdgcn_mfma_f32_16x16x32_f16(afb, bfr[t], c[1][t], 0, 0, 0);
        }

        if (pre) {
            float4v* dst = (float4v*)&tile[buf ^ 1][0];
            dst[tid * 2 + 0] = s0;
            dst[tid * 2 + 1] = s1;
        }
        __syncthreads();
        buf ^= 1;
    }

    Sa += __shfl_xor(Sa, 16, 64); Sa += __shfl_xor(Sa, 32, 64);
    Sb += __shfl_xor(Sb, 16, 64); Sb += __shfl_xor(Sb, 32, 64);
    if (q == 0) {
        pS[(size_t)jy * NN + rowbase + m]      = Sa;
        pS[(size_t)jy * NN + rowbase + 16 + m] = Sb;
    }
    #pragma unroll
    for (int rg = 0; rg < 2; ++rg)
        #pragma unroll
        for (int t = 0; t < 8; ++t)
            #pragma unroll
            for (int reg = 0; reg < 4; ++reg) {
                const int row = rowbase + rg * 16 + q * 4 + reg;
                pC[((size_t)jy * NN + row) * FOUT + t * 16 + m] = c[rg][t][reg];
            }
}

// ---------------------------------------------------------------------------
// Kernel 3: reduce J partials, normalize, ELU.
// ---------------------------------------------------------------------------
__global__ __launch_bounds__(256) void k_reduce(
    const float* __restrict__ pC, const float* __restrict__ pS,
    float* __restrict__ out, int J)
{
    const int idx = blockIdx.x * 256 + threadIdx.x;  // (row, col/4)
    const int row = idx >> 5;
    const int c4  = (idx & 31) * 4;
    float4v acc = (float4v){0.f, 0.f, 0.f, 0.f};
    float S = 0.f;
    for (int j = 0; j < J; ++j) {
        const float4v v = *(const float4v*)(pC + ((size_t)j * NN + row) * FOUT + c4);
        acc.x += v.x; acc.y += v.y; acc.z += v.z; acc.w += v.w;
        S += pS[(size_t)j * NN + row];
    }
    const float inv = 1.f / fmaxf(S, 1e-30f);
    float4v r;
    #pragma unroll
    for (int k = 0; k < 4; ++k) {
        const float v = acc[k] * inv;
        r[k] = (v > 0.f) ? v : (__expf(v) - 1.f);
    }
    *(float4v*)(out + (size_t)row * FOUT + c4) = r;
}

// ---------------------------------------------------------------------------
// Fallback (tiny ws): round-3 kernel, adapted to WhT2 j-tiled layout.
// ---------------------------------------------------------------------------
__global__ __launch_bounds__(256) void k_attn_fb(
    const int* __restrict__ adj,
    const _Float16* __restrict__ WhT2,
    const float* __restrict__ Wh1, const float* __restrict__ Wh2,
    const float* __restrict__ maxp,
    float* __restrict__ out)
{
    __shared__ __align__(16) float cbuf[4][8][64][4];
    __shared__ float sbuf[4][16];
    const int tid  = threadIdx.x;
    const int w    = tid >> 6;
    const int lane = tid & 63;
    const int m    = lane & 15;
    const int q    = lane >> 4;
    const int i    = blockIdx.x * 16 + m;

    const float wh1 = Wh1[i];
    const float tm = wh1 + maxp[0];
    const float Mi = fmaxf(tm, ALPHA * tm);

    float4v c[8];
    #pragma unroll
    for (int t = 0; t < 8; ++t) c[t] = (float4v){0.f, 0.f, 0.f, 0.f};
    float S = 0.f;
    const int* adjrow = adj + (size_t)i * NN;

    for (int j0 = w * (NN / 4); j0 < (w + 1) * (NN / 4); j0 += 32) {
        const int jb = j0 + q * 8;
        const int4v  a0 = *(const int4v*)(adjrow + jb);
        const int4v  a1 = *(const int4v*)(adjrow + jb + 4);
        const float4v w0 = *(const float4v*)(Wh2 + jb);
        const float4v w1 = *(const float4v*)(Wh2 + jb + 4);
        half8v bfr[8];
        #pragma unroll
        for (int t = 0; t < 8; ++t)
            bfr[t] = *(const half8v*)(WhT2 + (size_t)(j0 >> 5) * 4096 + (t * 16 + m) * 32 + q * 8);
        const float wvv[8] = {w0.x, w0.y, w0.z, w0.w, w1.x, w1.y, w1.z, w1.w};
        const int av[8] = {a0.x, a0.y, a0.z, a0.w, a1.x, a1.y, a1.z, a1.w};
        half8v af;
        #pragma unroll
        for (int jj = 0; jj < 8; ++jj) {
            float e = wh1 + wvv[jj]; e = fmaxf(e, ALPHA * e);
            const float p = av[jj] ? __expf(e - Mi) : 0.f;
            const _Float16 ph = (_Float16)p;
            af[jj] = ph; S += (float)ph;
        }
        #pragma unroll
        for (int t = 0; t < 8; ++t)
            c[t] = __builtin_amdgcn_mfma_f32_16x16x32_f16(af, bfr[t], c[t], 0, 0, 0);
    }
    S += __shfl_xor(S, 16, 64);
    S += __shfl_xor(S, 32, 64);
    if (lane < 16) sbuf[w][lane] = S;
    #pragma unroll
    for (int t = 0; t < 8; ++t) *(float4v*)&cbuf[w][t][lane][0] = c[t];
    __syncthreads();
    #pragma unroll
    for (int tt = 0; tt < 2; ++tt) {
        const int t = w * 2 + tt;
        float4v cs = *(const float4v*)&cbuf[0][t][lane][0];
        #pragma unroll
        for (int w2 = 1; w2 < 4; ++w2) {
            const float4v o = *(const float4v*)&cbuf[w2][t][lane][0];
            cs.x += o.x; cs.y += o.y; cs.z += o.z; cs.w += o.w;
        }
        #pragma unroll
        for (int reg = 0; reg < 4; ++reg) {
            const int mloc = q * 4 + reg;
            const float Sr = sbuf[0][mloc] + sbuf[1][mloc] + sbuf[2][mloc] + sbuf[3][mloc];
            const float v = cs[reg] / fmaxf(Sr, 1e-30f);
            out[(size_t)(blockIdx.x * 16 + mloc) * FOUT + t * 16 + m] =
                (v > 0.f) ? v : (__expf(v) - 1.f);
        }
    }
}

// ---------------------------------------------------------------------------
extern "C" void kernel_launch(void* const* d_in, const int* in_sizes, int n_in,
                              void* d_out, int out_size, void* d_ws, size_t ws_size,
                              hipStream_t stream) {
    const float* h   = (const float*)d_in[0];
    const int*   adj = (const int*)d_in[1];
    const float* W   = (const float*)d_in[2];
    const float* a   = (const float*)d_in[3];
    float* out = (float*)d_out;

    char* ws = (char*)d_ws;
    float* Wh1 = (float*)ws;                           // 49152
    float* Wh2 = (float*)(ws + 49152);                 // 49152
    float* mx  = (float*)(ws + 98304);                 // 256
    _Float16* WhT2 = (_Float16*)(ws + 98560);          // 3,145,728
    unsigned int* maskT = (unsigned int*)(ws + 3244288);  // 18,874,368
    const size_t base_need = 3244288ULL + 18874368ULL; // 22,118,656

    int J = 8;
    while (J > 1 &&
           base_need + (size_t)J * NN * 4 + (size_t)J * NN * FOUT * 4 > ws_size)
        J >>= 1;
    const bool ok =
        base_need + (size_t)NN * 4 + (size_t)NN * FOUT * 4 <= ws_size;

    k_wh  <<<NN / 16, 128, 0, stream>>>(h, W, a, WhT2, Wh1, Wh2);
    k_max <<<1, 256, 0, stream>>>(Wh2, mx);
    if (ok) {
        float* pS = (float*)(ws + base_need);
        float* pC = pS + (size_t)J * NN;
        k_pack<<<NN / 16, 256, 0, stream>>>(adj, maskT);
        k_attn<<<dim3(NN / 128, J), 256, 0, stream>>>(maskT, WhT2, Wh1, Wh2, mx, pC, pS);
        k_reduce<<<(NN * (FOUT / 4)) / 256, 256, 0, stream>>>(pC, pS, out, J);
    } else {
        k_attn_fb<<<NN / 16, 256, 0, stream>>>(adj, WhT2, Wh1, Wh2, mx, out);
    }
}

// Round 5
// 897.584 us; speedup vs baseline: 1.3596x; 1.3596x over previous
//
#include <hip/hip_runtime.h>

#define NN   12288
#define FIN  256
#define FOUT 128
#define ALPHA 0.2f

typedef __attribute__((ext_vector_type(8))) _Float16 half8v;
typedef __attribute__((ext_vector_type(4))) float float4v;
typedef __attribute__((ext_vector_type(4))) int   int4v;

// WhT2 layout: [node>>5][feat 0..127][node&31]  (_Float16)
//   -> one j-tile (32 nodes x 128 feats) is a contiguous 8 KB block.

// ---------------------------------------------------------------------------
// Kernel 1: Wh = h @ W (fp32): writes WhT2 (f16, j-tiled) + Wh1/Wh2 (fp32).
// One block = 16 nodes, 128 threads (thread t owns feature t).
// ---------------------------------------------------------------------------
__global__ __launch_bounds__(128) void k_wh(
    const float* __restrict__ h,
    const float* __restrict__ W,
    const float* __restrict__ a,
    _Float16* __restrict__ WhT2,
    float* __restrict__ Wh1, float* __restrict__ Wh2)
{
    __shared__ __align__(16) float hs[16 * FIN];   // 16 KB
    __shared__ float sP1[2][16], sP2[2][16];
    const int t = threadIdx.x;                     // 0..127
    const int row0 = blockIdx.x * 16;

    const float4v* hsrc = (const float4v*)(h + (size_t)row0 * FIN);
    float4v* hdst = (float4v*)hs;
    #pragma unroll
    for (int i = 0; i < 8; ++i) hdst[t + i * 128] = hsrc[t + i * 128];
    __syncthreads();

    float acc[16];
    #pragma unroll
    for (int r = 0; r < 16; ++r) acc[r] = 0.f;

    for (int k = 0; k < FIN; k += 4) {
        const float w0 = W[(k + 0) * FOUT + t];
        const float w1 = W[(k + 1) * FOUT + t];
        const float w2 = W[(k + 2) * FOUT + t];
        const float w3 = W[(k + 3) * FOUT + t];
        #pragma unroll
        for (int r = 0; r < 16; ++r) {
            const float4v hv = *(const float4v*)&hs[r * FIN + k];
            float s = acc[r];
            s = fmaf(hv.x, w0, s);
            s = fmaf(hv.y, w1, s);
            s = fmaf(hv.z, w2, s);
            s = fmaf(hv.w, w3, s);
            acc[r] = s;
        }
    }

    // WhT2[(row0+r)>>5][t][(row0+r)&31]; row0 mult of 16 -> contiguous r
    half8v pk0, pk1;
    #pragma unroll
    for (int r = 0; r < 8; ++r)  pk0[r] = (_Float16)acc[r];
    #pragma unroll
    for (int r = 0; r < 8; ++r)  pk1[r] = (_Float16)acc[8 + r];
    _Float16* dst = WhT2 + (size_t)(row0 >> 5) * 4096 + t * 32 + (row0 & 16);
    *(half8v*)(dst)     = pk0;
    *(half8v*)(dst + 8) = pk1;

    const float a1t = a[t];
    const float a2t = a[FOUT + t];
    const int lane = t & 63, wv = t >> 6;
    #pragma unroll
    for (int r = 0; r < 16; ++r) {
        float v1 = acc[r] * a1t;
        float v2 = acc[r] * a2t;
        #pragma unroll
        for (int off = 1; off < 64; off <<= 1) {
            v1 += __shfl_xor(v1, off, 64);
            v2 += __shfl_xor(v2, off, 64);
        }
        if (lane == 0) { sP1[wv][r] = v1; sP2[wv][r] = v2; }
    }
    __syncthreads();
    if (t < 16) {
        Wh1[row0 + t] = sP1[0][t] + sP1[1][t];
        Wh2[row0 + t] = sP2[0][t] + sP2[1][t];
    }
}

// ---------------------------------------------------------------------------
// Kernel 1b: maxWh2
// ---------------------------------------------------------------------------
__global__ __launch_bounds__(256) void k_max(
    const float* __restrict__ Wh2, float* __restrict__ outmax)
{
    __shared__ float sm[4];
    float m = -1e30f;
    for (int i = threadIdx.x; i < NN; i += 256) m = fmaxf(m, Wh2[i]);
    #pragma unroll
    for (int off = 1; off < 64; off <<= 1) m = fmaxf(m, __shfl_xor(m, off, 64));
    if ((threadIdx.x & 63) == 0) sm[threadIdx.x >> 6] = m;
    __syncthreads();
    if (threadIdx.x == 0)
        outmax[0] = fmaxf(fmaxf(sm[0], sm[1]), fmaxf(sm[2], sm[3]));
}

// ---------------------------------------------------------------------------
// Kernel 2: fused masked-softmax attention + PV GEMM (partials).
// Grid (NN/128, J). Block = 4 waves; wave w owns rows rowbase..rowbase+31
// (rowbase = bx*128 + w*32) over j-slice jy. adj is read DIRECTLY (each
// 64B line touched exactly once grid-wide; no pack pass — the ballot-chain
// pack kernel was latency-bound at 449us). Per iter the 8 KB WhT2 j-tile is
// double-buffer staged in LDS, shared by all 4 waves. P built in MFMA
// A-layout in-register. Writes UN-normalized partial C + S; k_reduce ends.
// ---------------------------------------------------------------------------
__global__ __launch_bounds__(256, 3) void k_attn(
    const int* __restrict__ adj,
    const _Float16* __restrict__ WhT2,
    const float* __restrict__ Wh1, const float* __restrict__ Wh2,
    const float* __restrict__ maxp,
    float* __restrict__ pC, float* __restrict__ pS)
{
    __shared__ __align__(16) _Float16 tile[2][128 * 32];   // 2 x 8 KB
    const int tid  = threadIdx.x;
    const int w    = tid >> 6;
    const int lane = tid & 63;
    const int m    = lane & 15;
    const int q    = lane >> 4;
    const int rowbase = blockIdx.x * 128 + w * 32;
    const int J    = gridDim.y;
    const int jy   = blockIdx.y;
    const int jlen = NN / J;
    const int jbeg = jy * jlen;
    const int iters = jlen / 32;

    const float mxv  = maxp[0];
    const float wh1a = Wh1[rowbase + m];
    const float wh1b = Wh1[rowbase + 16 + m];
    const float tma = wh1a + mxv; const float Ma = fmaxf(tma, ALPHA * tma);
    const float tmb = wh1b + mxv; const float Mb = fmaxf(tmb, ALPHA * tmb);

    const int* rowA = adj + (size_t)(rowbase + m) * NN;
    const int* rowB = adj + (size_t)(rowbase + 16 + m) * NN;

    float4v c[2][8];
    #pragma unroll
    for (int rg = 0; rg < 2; ++rg)
        #pragma unroll
        for (int t = 0; t < 8; ++t) c[rg][t] = (float4v){0.f, 0.f, 0.f, 0.f};
    float Sa = 0.f, Sb = 0.f;

    // stage first tile
    {
        const float4v* src = (const float4v*)(WhT2 + (size_t)(jbeg >> 5) * 4096);
        float4v* dst = (float4v*)&tile[0][0];
        dst[tid * 2 + 0] = src[tid * 2 + 0];
        dst[tid * 2 + 1] = src[tid * 2 + 1];
    }
    __syncthreads();

    int buf = 0;
    for (int it = 0; it < iters; ++it) {
        const int j0 = jbeg + it * 32;
        const int jb = j0 + q * 8;
        const bool pre = (it + 1 < iters);
        float4v s0, s1;
        if (pre) {
            const float4v* src = (const float4v*)(WhT2 + (size_t)((j0 + 32) >> 5) * 4096);
            s0 = src[tid * 2 + 0];
            s1 = src[tid * 2 + 1];
        }

        // adj octets for this lane's two rows (coalesced: 4 q-lanes cover
        // one 128 B row segment); plenty of independent loads in flight.
        const int4v aa0 = *(const int4v*)(rowA + jb);
        const int4v aa1 = *(const int4v*)(rowA + jb + 4);
        const int4v ab0 = *(const int4v*)(rowB + jb);
        const int4v ab1 = *(const int4v*)(rowB + jb + 4);
        const float4v w0 = *(const float4v*)(Wh2 + jb);
        const float4v w1 = *(const float4v*)(Wh2 + jb + 4);
        const float wv[8] = {w0.x, w0.y, w0.z, w0.w, w1.x, w1.y, w1.z, w1.w};
        const int   ava[8] = {aa0.x, aa0.y, aa0.z, aa0.w, aa1.x, aa1.y, aa1.z, aa1.w};
        const int   avb[8] = {ab0.x, ab0.y, ab0.z, ab0.w, ab1.x, ab1.y, ab1.z, ab1.w};

        half8v afa, afb;
        #pragma unroll
        for (int jj = 0; jj < 8; ++jj) {
            float e = wh1a + wv[jj]; e = fmaxf(e, ALPHA * e);
            const float p = ava[jj] ? __expf(e - Ma) : 0.f;
            const _Float16 ph = (_Float16)p;
            afa[jj] = ph; Sa += (float)ph;
        }
        #pragma unroll
        for (int jj = 0; jj < 8; ++jj) {
            float e = wh1b + wv[jj]; e = fmaxf(e, ALPHA * e);
            const float p = avb[jj] ? __expf(e - Mb) : 0.f;
            const _Float16 ph = (_Float16)p;
            afb[jj] = ph; Sb += (float)ph;
        }

        half8v bfr[8];
        #pragma unroll
        for (int t = 0; t < 8; ++t)
            bfr[t] = *(const half8v*)&tile[buf][(t * 16 + m) * 32 + q * 8];

        #pragma unroll
        for (int t = 0; t < 8; ++t) {
            c[0][t] = __builtin_amdgcn_mfma_f32_16x16x32_f16(afa, bfr[t], c[0][t], 0, 0, 0);
            c[1][t] = __builtin_amdgcn_mfma_f32_16x16x32_f16(afb, bfr[t], c[1][t], 0, 0, 0);
        }

        if (pre) {
            float4v* dst = (float4v*)&tile[buf ^ 1][0];
            dst[tid * 2 + 0] = s0;
            dst[tid * 2 + 1] = s1;
        }
        __syncthreads();
        buf ^= 1;
    }

    Sa += __shfl_xor(Sa, 16, 64); Sa += __shfl_xor(Sa, 32, 64);
    Sb += __shfl_xor(Sb, 16, 64); Sb += __shfl_xor(Sb, 32, 64);
    if (q == 0) {
        pS[(size_t)jy * NN + rowbase + m]      = Sa;
        pS[(size_t)jy * NN + rowbase + 16 + m] = Sb;
    }
    #pragma unroll
    for (int rg = 0; rg < 2; ++rg)
        #pragma unroll
        for (int t = 0; t < 8; ++t)
            #pragma unroll
            for (int reg = 0; reg < 4; ++reg) {
                const int row = rowbase + rg * 16 + q * 4 + reg;
                pC[((size_t)jy * NN + row) * FOUT + t * 16 + m] = c[rg][t][reg];
            }
}

// ---------------------------------------------------------------------------
// Kernel 3: reduce J partials, normalize, ELU.
// ---------------------------------------------------------------------------
__global__ __launch_bounds__(256) void k_reduce(
    const float* __restrict__ pC, const float* __restrict__ pS,
    float* __restrict__ out, int J)
{
    const int idx = blockIdx.x * 256 + threadIdx.x;  // (row, col/4)
    const int row = idx >> 5;
    const int c4  = (idx & 31) * 4;
    float4v acc = (float4v){0.f, 0.f, 0.f, 0.f};
    float S = 0.f;
    for (int j = 0; j < J; ++j) {
        const float4v v = *(const float4v*)(pC + ((size_t)j * NN + row) * FOUT + c4);
        acc.x += v.x; acc.y += v.y; acc.z += v.z; acc.w += v.w;
        S += pS[(size_t)j * NN + row];
    }
    const float inv = 1.f / fmaxf(S, 1e-30f);
    float4v r;
    #pragma unroll
    for (int k = 0; k < 4; ++k) {
        const float v = acc[k] * inv;
        r[k] = (v > 0.f) ? v : (__expf(v) - 1.f);
    }
    *(float4v*)(out + (size_t)row * FOUT + c4) = r;
}

// ---------------------------------------------------------------------------
// Fallback (tiny ws): single-pass, adapted to WhT2 j-tiled layout.
// ---------------------------------------------------------------------------
__global__ __launch_bounds__(256) void k_attn_fb(
    const int* __restrict__ adj,
    const _Float16* __restrict__ WhT2,
    const float* __restrict__ Wh1, const float* __restrict__ Wh2,
    const float* __restrict__ maxp,
    float* __restrict__ out)
{
    __shared__ __align__(16) float cbuf[4][8][64][4];
    __shared__ float sbuf[4][16];
    const int tid  = threadIdx.x;
    const int w    = tid >> 6;
    const int lane = tid & 63;
    const int m    = lane & 15;
    const int q    = lane >> 4;
    const int i    = blockIdx.x * 16 + m;

    const float wh1 = Wh1[i];
    const float tm = wh1 + maxp[0];
    const float Mi = fmaxf(tm, ALPHA * tm);

    float4v c[8];
    #pragma unroll
    for (int t = 0; t < 8; ++t) c[t] = (float4v){0.f, 0.f, 0.f, 0.f};
    float S = 0.f;
    const int* adjrow = adj + (size_t)i * NN;

    for (int j0 = w * (NN / 4); j0 < (w + 1) * (NN / 4); j0 += 32) {
        const int jb = j0 + q * 8;
        const int4v  a0 = *(const int4v*)(adjrow + jb);
        const int4v  a1 = *(const int4v*)(adjrow + jb + 4);
        const float4v w0 = *(const float4v*)(Wh2 + jb);
        const float4v w1 = *(const float4v*)(Wh2 + jb + 4);
        half8v bfr[8];
        #pragma unroll
        for (int t = 0; t < 8; ++t)
            bfr[t] = *(const half8v*)(WhT2 + (size_t)(j0 >> 5) * 4096 + (t * 16 + m) * 32 + q * 8);
        const float wvv[8] = {w0.x, w0.y, w0.z, w0.w, w1.x, w1.y, w1.z, w1.w};
        const int av[8] = {a0.x, a0.y, a0.z, a0.w, a1.x, a1.y, a1.z, a1.w};
        half8v af;
        #pragma unroll
        for (int jj = 0; jj < 8; ++jj) {
            float e = wh1 + wvv[jj]; e = fmaxf(e, ALPHA * e);
            const float p = av[jj] ? __expf(e - Mi) : 0.f;
            const _Float16 ph = (_Float16)p;
            af[jj] = ph; S += (float)ph;
        }
        #pragma unroll
        for (int t = 0; t < 8; ++t)
            c[t] = __builtin_amdgcn_mfma_f32_16x16x32_f16(af, bfr[t], c[t], 0, 0, 0);
    }
    S += __shfl_xor(S, 16, 64);
    S += __shfl_xor(S, 32, 64);
    if (lane < 16) sbuf[w][lane] = S;
    #pragma unroll
    for (int t = 0; t < 8; ++t) *(float4v*)&cbuf[w][t][lane][0] = c[t];
    __syncthreads();
    #pragma unroll
    for (int tt = 0; tt < 2; ++tt) {
        const int t = w * 2 + tt;
        float4v cs = *(const float4v*)&cbuf[0][t][lane][0];
        #pragma unroll
        for (int w2 = 1; w2 < 4; ++w2) {
            const float4v o = *(const float4v*)&cbuf[w2][t][lane][0];
            cs.x += o.x; cs.y += o.y; cs.z += o.z; cs.w += o.w;
        }
        #pragma unroll
        for (int reg = 0; reg < 4; ++reg) {
            const int mloc = q * 4 + reg;
            const float Sr = sbuf[0][mloc] + sbuf[1][mloc] + sbuf[2][mloc] + sbuf[3][mloc];
            const float v = cs[reg] / fmaxf(Sr, 1e-30f);
            out[(size_t)(blockIdx.x * 16 + mloc) * FOUT + t * 16 + m] =
                (v > 0.f) ? v : (__expf(v) - 1.f);
        }
    }
}

// ---------------------------------------------------------------------------
extern "C" void kernel_launch(void* const* d_in, const int* in_sizes, int n_in,
                              void* d_out, int out_size, void* d_ws, size_t ws_size,
                              hipStream_t stream) {
    const float* h   = (const float*)d_in[0];
    const int*   adj = (const int*)d_in[1];
    const float* W   = (const float*)d_in[2];
    const float* a   = (const float*)d_in[3];
    float* out = (float*)d_out;

    char* ws = (char*)d_ws;
    float* Wh1 = (float*)ws;                           // 49152
    float* Wh2 = (float*)(ws + 49152);                 // 49152
    float* mx  = (float*)(ws + 98304);                 // 256
    _Float16* WhT2 = (_Float16*)(ws + 98560);          // 3,145,728
    const size_t base_need = 98560ULL + 3145728ULL;    // 3,244,288

    int J = 8;
    while (J > 1 &&
           base_need + (size_t)J * NN * 4 + (size_t)J * NN * FOUT * 4 > ws_size)
        J >>= 1;
    const bool ok =
        base_need + (size_t)NN * 4 + (size_t)NN * FOUT * 4 <= ws_size;

    k_wh  <<<NN / 16, 128, 0, stream>>>(h, W, a, WhT2, Wh1, Wh2);
    k_max <<<1, 256, 0, stream>>>(Wh2, mx);
    if (ok) {
        float* pS = (float*)(ws + base_need);
        float* pC = pS + (size_t)J * NN;
        k_attn<<<dim3(NN / 128, J), 256, 0, stream>>>(adj, WhT2, Wh1, Wh2, mx, pC, pS);
        k_reduce<<<(NN * (FOUT / 4)) / 256, 256, 0, stream>>>(pC, pS, out, J);
    } else {
        k_attn_fb<<<NN / 16, 256, 0, stream>>>(adj, WhT2, Wh1, Wh2, mx, out);
    }
}

// Round 6
// 880.937 us; speedup vs baseline: 1.3853x; 1.0189x over previous
//
#include <hip/hip_runtime.h>

#define NN   12288
#define FIN  256
#define FOUT 128
#define ALPHA 0.2f

typedef __attribute__((ext_vector_type(8))) _Float16 half8v;
typedef __attribute__((ext_vector_type(4))) float float4v;
typedef __attribute__((ext_vector_type(4))) int   int4v;

// WhT2 layout: [node>>5][feat 0..127][node&31]  (_Float16)
//   -> one j-tile (32 nodes x 128 feats) is a contiguous 8 KB block.

#define GLL16(gp, lp)                                                          \
    __builtin_amdgcn_global_load_lds(                                          \
        (const __attribute__((address_space(1))) void*)(gp),                   \
        (__attribute__((address_space(3))) void*)(lp), 16, 0, 0)

// ---------------------------------------------------------------------------
// Kernel 1: Wh = h @ W (fp32): writes WhT2 (f16, j-tiled) + Wh1/Wh2 (fp32).
// ---------------------------------------------------------------------------
__global__ __launch_bounds__(128) void k_wh(
    const float* __restrict__ h,
    const float* __restrict__ W,
    const float* __restrict__ a,
    _Float16* __restrict__ WhT2,
    float* __restrict__ Wh1, float* __restrict__ Wh2)
{
    __shared__ __align__(16) float hs[16 * FIN];   // 16 KB
    __shared__ float sP1[2][16], sP2[2][16];
    const int t = threadIdx.x;                     // 0..127
    const int row0 = blockIdx.x * 16;

    const float4v* hsrc = (const float4v*)(h + (size_t)row0 * FIN);
    float4v* hdst = (float4v*)hs;
    #pragma unroll
    for (int i = 0; i < 8; ++i) hdst[t + i * 128] = hsrc[t + i * 128];
    __syncthreads();

    float acc[16];
    #pragma unroll
    for (int r = 0; r < 16; ++r) acc[r] = 0.f;

    for (int k = 0; k < FIN; k += 4) {
        const float w0 = W[(k + 0) * FOUT + t];
        const float w1 = W[(k + 1) * FOUT + t];
        const float w2 = W[(k + 2) * FOUT + t];
        const float w3 = W[(k + 3) * FOUT + t];
        #pragma unroll
        for (int r = 0; r < 16; ++r) {
            const float4v hv = *(const float4v*)&hs[r * FIN + k];
            float s = acc[r];
            s = fmaf(hv.x, w0, s);
            s = fmaf(hv.y, w1, s);
            s = fmaf(hv.z, w2, s);
            s = fmaf(hv.w, w3, s);
            acc[r] = s;
        }
    }

    half8v pk0, pk1;
    #pragma unroll
    for (int r = 0; r < 8; ++r)  pk0[r] = (_Float16)acc[r];
    #pragma unroll
    for (int r = 0; r < 8; ++r)  pk1[r] = (_Float16)acc[8 + r];
    _Float16* dst = WhT2 + (size_t)(row0 >> 5) * 4096 + t * 32 + (row0 & 16);
    *(half8v*)(dst)     = pk0;
    *(half8v*)(dst + 8) = pk1;

    const float a1t = a[t];
    const float a2t = a[FOUT + t];
    const int lane = t & 63, wv = t >> 6;
    #pragma unroll
    for (int r = 0; r < 16; ++r) {
        float v1 = acc[r] * a1t;
        float v2 = acc[r] * a2t;
        #pragma unroll
        for (int off = 1; off < 64; off <<= 1) {
            v1 += __shfl_xor(v1, off, 64);
            v2 += __shfl_xor(v2, off, 64);
        }
        if (lane == 0) { sP1[wv][r] = v1; sP2[wv][r] = v2; }
    }
    __syncthreads();
    if (t < 16) {
        Wh1[row0 + t] = sP1[0][t] + sP1[1][t];
        Wh2[row0 + t] = sP2[0][t] + sP2[1][t];
    }
}

// ---------------------------------------------------------------------------
// Kernel 1b: maxWh2
// ---------------------------------------------------------------------------
__global__ __launch_bounds__(256) void k_max(
    const float* __restrict__ Wh2, float* __restrict__ outmax)
{
    __shared__ float sm[4];
    float m = -1e30f;
    for (int i = threadIdx.x; i < NN; i += 256) m = fmaxf(m, Wh2[i]);
    #pragma unroll
    for (int off = 1; off < 64; off <<= 1) m = fmaxf(m, __shfl_xor(m, off, 64));
    if ((threadIdx.x & 63) == 0) sm[threadIdx.x >> 6] = m;
    __syncthreads();
    if (threadIdx.x == 0)
        outmax[0] = fmaxf(fmaxf(sm[0], sm[1]), fmaxf(sm[2], sm[3]));
}

// ---------------------------------------------------------------------------
// P-fragment builder: leaky -> mask -> exp(e-M); f16 numerator, f32 row sum.
// ---------------------------------------------------------------------------
static __device__ __forceinline__ half8v build_p(
    const int4v a0, const int4v a1, const float* wvv,
    const float wh1, const float M, float& S)
{
    const int av[8] = {a0.x, a0.y, a0.z, a0.w, a1.x, a1.y, a1.z, a1.w};
    half8v af;
    #pragma unroll
    for (int jj = 0; jj < 8; ++jj) {
        float e = wh1 + wvv[jj];
        e = fmaxf(e, ALPHA * e);
        const float p = av[jj] ? __expf(e - M) : 0.f;
        af[jj] = (_Float16)p;
        S += p;
    }
    return af;
}

// ---------------------------------------------------------------------------
// Kernel 2: fused masked-softmax attention + PV GEMM (partials).
// Grid (NN/128, J). Block = 4 waves; wave w owns rows rowbase..rowbase+31.
// Per barrier period: 64 j. WhT2 tiles (2 x 8 KB) staged via
// global_load_lds width=16 (wave w fills its contiguous 4 KB quarter:
// wave-uniform LDS base + lane*16 — the required DMA pattern). adj is read
// directly with nontemporal loads (zero reuse; keeps L2 for WhT2/Wh2).
// Mi = leaky(Wh1_i + max_j Wh2_j) >= row max => exp<=1, single pass.
// Writes UN-normalized partial C + S; k_reduce finishes.
// ---------------------------------------------------------------------------
__global__ __launch_bounds__(256, 3) void k_attn(
    const int* __restrict__ adj,
    const _Float16* __restrict__ WhT2,
    const float* __restrict__ Wh1, const float* __restrict__ Wh2,
    const float* __restrict__ maxp,
    float* __restrict__ pC, float* __restrict__ pS)
{
    __shared__ __align__(16) _Float16 tile[2][2][4096];   // 2 periods x 16 KB
    const int tid  = threadIdx.x;
    const int w    = tid >> 6;
    const int lane = tid & 63;
    const int m    = lane & 15;
    const int q    = lane >> 4;
    const int rowbase = blockIdx.x * 128 + w * 32;
    const int J    = gridDim.y;
    const int jy   = blockIdx.y;
    const int jlen = NN / J;
    const int jbeg = jy * jlen;
    const int iters = jlen / 64;

    const float mxv  = maxp[0];
    const float wh1a = Wh1[rowbase + m];
    const float wh1b = Wh1[rowbase + 16 + m];
    const float tma = wh1a + mxv; const float Ma = fmaxf(tma, ALPHA * tma);
    const float tmb = wh1b + mxv; const float Mb = fmaxf(tmb, ALPHA * tmb);

    const int* rowA = adj + (size_t)(rowbase + m) * NN;
    const int* rowB = adj + (size_t)(rowbase + 16 + m) * NN;

    float4v c[2][8];
    #pragma unroll
    for (int rg = 0; rg < 2; ++rg)
        #pragma unroll
        for (int t = 0; t < 8; ++t) c[rg][t] = (float4v){0.f, 0.f, 0.f, 0.f};
    float Sa = 0.f, Sb = 0.f;

    // stage period 0 (16 KB) via LDS-DMA: wave w covers float4 [w*256, w*256+256)
    {
        const float4v* grp = (const float4v*)(WhT2 + (size_t)(jbeg >> 5) * 4096);
        float4v* lb = (float4v*)&tile[0][0][0];
        #pragma unroll
        for (int k = 0; k < 4; ++k)
            GLL16(grp + (w * 4 + k) * 64 + lane, lb + (w * 4 + k) * 64);
    }
    __syncthreads();

    int buf = 0;
    for (int it = 0; it < iters; ++it) {
        const int j0 = jbeg + it * 64;

        // prefetch next period straight into the other LDS buffer (async DMA)
        if (it + 1 < iters) {
            const float4v* grp =
                (const float4v*)(WhT2 + (size_t)((j0 + 64) >> 5) * 4096);
            float4v* lb = (float4v*)&tile[buf ^ 1][0][0];
            #pragma unroll
            for (int k = 0; k < 4; ++k)
                GLL16(grp + (w * 4 + k) * 64 + lane, lb + (w * 4 + k) * 64);
        }

        // adj octets (nontemporal, coalesced 128B/row across q-lanes) + Wh2
        const int jb0 = j0 + q * 8;
        const int jb1 = j0 + 32 + q * 8;
        const int4v aA0 = __builtin_nontemporal_load((const int4v*)(rowA + jb0));
        const int4v aA1 = __builtin_nontemporal_load((const int4v*)(rowA + jb0 + 4));
        const int4v aA2 = __builtin_nontemporal_load((const int4v*)(rowA + jb1));
        const int4v aA3 = __builtin_nontemporal_load((const int4v*)(rowA + jb1 + 4));
        const int4v aB0 = __builtin_nontemporal_load((const int4v*)(rowB + jb0));
        const int4v aB1 = __builtin_nontemporal_load((const int4v*)(rowB + jb0 + 4));
        const int4v aB2 = __builtin_nontemporal_load((const int4v*)(rowB + jb1));
        const int4v aB3 = __builtin_nontemporal_load((const int4v*)(rowB + jb1 + 4));
        const float4v w00 = *(const float4v*)(Wh2 + jb0);
        const float4v w01 = *(const float4v*)(Wh2 + jb0 + 4);
        const float4v w10 = *(const float4v*)(Wh2 + jb1);
        const float4v w11 = *(const float4v*)(Wh2 + jb1 + 4);
        const float wv0[8] = {w00.x, w00.y, w00.z, w00.w, w01.x, w01.y, w01.z, w01.w};
        const float wv1[8] = {w10.x, w10.y, w10.z, w10.w, w11.x, w11.y, w11.z, w11.w};

        const half8v afa0 = build_p(aA0, aA1, wv0, wh1a, Ma, Sa);
        const half8v afa1 = build_p(aA2, aA3, wv1, wh1a, Ma, Sa);
        const half8v afb0 = build_p(aB0, aB1, wv0, wh1b, Mb, Sb);
        const half8v afb1 = build_p(aB2, aB3, wv1, wh1b, Mb, Sb);

        #pragma unroll
        for (int t = 0; t < 8; ++t) {
            const half8v b = *(const half8v*)&tile[buf][0][(t * 16 + m) * 32 + q * 8];
            c[0][t] = __builtin_amdgcn_mfma_f32_16x16x32_f16(afa0, b, c[0][t], 0, 0, 0);
            c[1][t] = __builtin_amdgcn_mfma_f32_16x16x32_f16(afb0, b, c[1][t], 0, 0, 0);
        }
        #pragma unroll
        for (int t = 0; t < 8; ++t) {
            const half8v b = *(const half8v*)&tile[buf][1][(t * 16 + m) * 32 + q * 8];
            c[0][t] = __builtin_amdgcn_mfma_f32_16x16x32_f16(afa1, b, c[0][t], 0, 0, 0);
            c[1][t] = __builtin_amdgcn_mfma_f32_16x16x32_f16(afb1, b, c[1][t], 0, 0, 0);
        }

        __syncthreads();
        buf ^= 1;
    }

    Sa += __shfl_xor(Sa, 16, 64); Sa += __shfl_xor(Sa, 32, 64);
    Sb += __shfl_xor(Sb, 16, 64); Sb += __shfl_xor(Sb, 32, 64);
    if (q == 0) {
        pS[(size_t)jy * NN + rowbase + m]      = Sa;
        pS[(size_t)jy * NN + rowbase + 16 + m] = Sb;
    }
    #pragma unroll
    for (int rg = 0; rg < 2; ++rg)
        #pragma unroll
        for (int t = 0; t < 8; ++t)
            #pragma unroll
            for (int reg = 0; reg < 4; ++reg) {
                const int row = rowbase + rg * 16 + q * 4 + reg;
                pC[((size_t)jy * NN + row) * FOUT + t * 16 + m] = c[rg][t][reg];
            }
}

// ---------------------------------------------------------------------------
// Kernel 3: reduce J partials, normalize, ELU.
// ---------------------------------------------------------------------------
__global__ __launch_bounds__(256) void k_reduce(
    const float* __restrict__ pC, const float* __restrict__ pS,
    float* __restrict__ out, int J)
{
    const int idx = blockIdx.x * 256 + threadIdx.x;  // (row, col/4)
    const int row = idx >> 5;
    const int c4  = (idx & 31) * 4;
    float4v acc = (float4v){0.f, 0.f, 0.f, 0.f};
    float S = 0.f;
    for (int j = 0; j < J; ++j) {
        const float4v v = *(const float4v*)(pC + ((size_t)j * NN + row) * FOUT + c4);
        acc.x += v.x; acc.y += v.y; acc.z += v.z; acc.w += v.w;
        S += pS[(size_t)j * NN + row];
    }
    const float inv = 1.f / fmaxf(S, 1e-30f);
    float4v r;
    #pragma unroll
    for (int k = 0; k < 4; ++k) {
        const float v = acc[k] * inv;
        r[k] = (v > 0.f) ? v : (__expf(v) - 1.f);
    }
    *(float4v*)(out + (size_t)row * FOUT + c4) = r;
}

// ---------------------------------------------------------------------------
// Fallback (tiny ws): single-pass, WhT2 j-tiled layout.
// ---------------------------------------------------------------------------
__global__ __launch_bounds__(256) void k_attn_fb(
    const int* __restrict__ adj,
    const _Float16* __restrict__ WhT2,
    const float* __restrict__ Wh1, const float* __restrict__ Wh2,
    const float* __restrict__ maxp,
    float* __restrict__ out)
{
    __shared__ __align__(16) float cbuf[4][8][64][4];
    __shared__ float sbuf[4][16];
    const int tid  = threadIdx.x;
    const int w    = tid >> 6;
    const int lane = tid & 63;
    const int m    = lane & 15;
    const int q    = lane >> 4;
    const int i    = blockIdx.x * 16 + m;

    const float wh1 = Wh1[i];
    const float tm = wh1 + maxp[0];
    const float Mi = fmaxf(tm, ALPHA * tm);

    float4v c[8];
    #pragma unroll
    for (int t = 0; t < 8; ++t) c[t] = (float4v){0.f, 0.f, 0.f, 0.f};
    float S = 0.f;
    const int* adjrow = adj + (size_t)i * NN;

    for (int j0 = w * (NN / 4); j0 < (w + 1) * (NN / 4); j0 += 32) {
        const int jb = j0 + q * 8;
        const int4v  a0 = *(const int4v*)(adjrow + jb);
        const int4v  a1 = *(const int4v*)(adjrow + jb + 4);
        const float4v w0 = *(const float4v*)(Wh2 + jb);
        const float4v w1 = *(const float4v*)(Wh2 + jb + 4);
        half8v bfr[8];
        #pragma unroll
        for (int t = 0; t < 8; ++t)
            bfr[t] = *(const half8v*)(WhT2 + (size_t)(j0 >> 5) * 4096 + (t * 16 + m) * 32 + q * 8);
        const float wvv[8] = {w0.x, w0.y, w0.z, w0.w, w1.x, w1.y, w1.z, w1.w};
        const half8v af = build_p(a0, a1, wvv, wh1, Mi, S);
        #pragma unroll
        for (int t = 0; t < 8; ++t)
            c[t] = __builtin_amdgcn_mfma_f32_16x16x32_f16(af, bfr[t], c[t], 0, 0, 0);
    }
    S += __shfl_xor(S, 16, 64);
    S += __shfl_xor(S, 32, 64);
    if (lane < 16) sbuf[w][lane] = S;
    #pragma unroll
    for (int t = 0; t < 8; ++t) *(float4v*)&cbuf[w][t][lane][0] = c[t];
    __syncthreads();
    #pragma unroll
    for (int tt = 0; tt < 2; ++tt) {
        const int t = w * 2 + tt;
        float4v cs = *(const float4v*)&cbuf[0][t][lane][0];
        #pragma unroll
        for (int w2 = 1; w2 < 4; ++w2) {
            const float4v o = *(const float4v*)&cbuf[w2][t][lane][0];
            cs.x += o.x; cs.y += o.y; cs.z += o.z; cs.w += o.w;
        }
        #pragma unroll
        for (int reg = 0; reg < 4; ++reg) {
            const int mloc = q * 4 + reg;
            const float Sr = sbuf[0][mloc] + sbuf[1][mloc] + sbuf[2][mloc] + sbuf[3][mloc];
            const float v = cs[reg] / fmaxf(Sr, 1e-30f);
            out[(size_t)(blockIdx.x * 16 + mloc) * FOUT + t * 16 + m] =
                (v > 0.f) ? v : (__expf(v) - 1.f);
        }
    }
}

// ---------------------------------------------------------------------------
extern "C" void kernel_launch(void* const* d_in, const int* in_sizes, int n_in,
                              void* d_out, int out_size, void* d_ws, size_t ws_size,
                              hipStream_t stream) {
    const float* h   = (const float*)d_in[0];
    const int*   adj = (const int*)d_in[1];
    const float* W   = (const float*)d_in[2];
    const float* a   = (const float*)d_in[3];
    float* out = (float*)d_out;

    char* ws = (char*)d_ws;
    float* Wh1 = (float*)ws;                           // 49152
    float* Wh2 = (float*)(ws + 49152);                 // 49152
    float* mx  = (float*)(ws + 98304);                 // 256
    _Float16* WhT2 = (_Float16*)(ws + 98560);          // 3,145,728
    const size_t base_need = 98560ULL + 3145728ULL;    // 3,244,288

    int J = 8;
    while (J > 1 &&
           base_need + (size_t)J * NN * 4 + (size_t)J * NN * FOUT * 4 > ws_size)
        J >>= 1;
    const bool ok =
        base_need + (size_t)NN * 4 + (size_t)NN * FOUT * 4 <= ws_size;

    k_wh  <<<NN / 16, 128, 0, stream>>>(h, W, a, WhT2, Wh1, Wh2);
    k_max <<<1, 256, 0, stream>>>(Wh2, mx);
    if (ok) {
        float* pS = (float*)(ws + base_need);
        float* pC = pS + (size_t)J * NN;
        k_attn<<<dim3(NN / 128, J), 256, 0, stream>>>(adj, WhT2, Wh1, Wh2, mx, pC, pS);
        k_reduce<<<(NN * (FOUT / 4)) / 256, 256, 0, stream>>>(pC, pS, out, J);
    } else {
        k_attn_fb<<<NN / 16, 256, 0, stream>>>(adj, WhT2, Wh1, Wh2, mx, out);
    }
}